// Round 1
// baseline (148.240 us; speedup 1.0000x reference)
//
#include <hip/hip_runtime.h>

// SpatialCoherenceLoss: mean over all (i,j) of exp(-||s_i-s_j||^2/0.01) * ||p_i-p_j||^2
// N=8192, D=64, C=2, fp32.
// Strategy (R1 baseline): fused pair loop. Wave = 64 distinct i (p_i in VGPRs),
// wave-uniform j loop -> p_j/sq_j/s_j become scalar s_loads (SGPR broadcast),
// so inner loop is 64 v_fmac (v,s) + ~10 VALU ops per pair. Compute-bound at
// the fp32 vector FMA floor (~55us for 4.3G FMA).

#define NPTS 8192
#define DIM  64

constexpr float kInvScale = 100.0f;          // 1 / 0.01
constexpr int   IB = 128;                    // i-blocks of 64 rows
constexpr int   JS = 16;                     // j-split groups per i-block
constexpr int   NBLOCKS = IB * JS;           // 2048 blocks
constexpr int   WPB = 4;                     // waves per block
constexpr int   JCHUNK = NPTS / (JS * WPB);  // 128 j per wave

__global__ void scl_sq_kernel(const float* __restrict__ pred,
                              float* __restrict__ sq) {
    int i = blockIdx.x * blockDim.x + threadIdx.x;
    if (i < NPTS) {
        const float4* p = (const float4*)(pred + (size_t)i * DIM);
        float s = 0.f;
        #pragma unroll
        for (int k = 0; k < DIM / 4; ++k) {
            float4 v = p[k];
            s += v.x * v.x + v.y * v.y + v.z * v.z + v.w * v.w;
        }
        sq[i] = s;
    }
}

__launch_bounds__(256, 4)
__global__ void scl_main_kernel(const float* __restrict__ pred,
                                const float* __restrict__ spat,
                                const float* __restrict__ sq,
                                float* __restrict__ partial) {
    const int lane = threadIdx.x & 63;
    const int wave = threadIdx.x >> 6;
    const int ib   = blockIdx.x & (IB - 1);
    const int js   = blockIdx.x >> 7;          // blockIdx.x / IB
    const int i    = ib * 64 + lane;

    // p_i -> 64 VGPRs
    float pi[DIM];
    const float4* prow = (const float4*)(pred + (size_t)i * DIM);
    #pragma unroll
    for (int k = 0; k < DIM / 4; ++k) {
        float4 v = prow[k];
        pi[4 * k + 0] = v.x; pi[4 * k + 1] = v.y;
        pi[4 * k + 2] = v.z; pi[4 * k + 3] = v.w;
    }
    const float sqi = sq[i];
    const float six = spat[2 * i];
    const float siy = spat[2 * i + 1];

    // wave-uniform j chunk (readfirstlane forces scalarization of j loads)
    const int chunk = __builtin_amdgcn_readfirstlane(js * WPB + wave);
    const int j0 = chunk * JCHUNK;

    float acc = 0.f;
    for (int jj = 0; jj < JCHUNK; ++jj) {
        const int j = j0 + jj;                  // uniform
        const float* __restrict__ pj = pred + (size_t)j * DIM;
        const float sjx = spat[2 * j];
        const float sjy = spat[2 * j + 1];
        const float sqj = sq[j];

        float d0 = 0.f, d1 = 0.f, d2 = 0.f, d3 = 0.f;
        #pragma unroll
        for (int k = 0; k < DIM; k += 4) {
            d0 = fmaf(pi[k + 0], pj[k + 0], d0);
            d1 = fmaf(pi[k + 1], pj[k + 1], d1);
            d2 = fmaf(pi[k + 2], pj[k + 2], d2);
            d3 = fmaf(pi[k + 3], pj[k + 3], d3);
        }
        const float dot = (d0 + d1) + (d2 + d3);

        const float dx = six - sjx;
        const float dy = siy - sjy;
        const float dist2 = fmaf(dx, dx, dy * dy);
        const float w = __expf(-kInvScale * dist2);
        const float pd = sqi + sqj - 2.f * dot;
        acc = fmaf(w, pd, acc);
    }

    // wave reduce
    #pragma unroll
    for (int off = 32; off > 0; off >>= 1)
        acc += __shfl_down(acc, off, 64);

    __shared__ float lds_red[WPB];
    if (lane == 0) lds_red[wave] = acc;
    __syncthreads();
    if (threadIdx.x == 0) {
        float s = 0.f;
        #pragma unroll
        for (int w2 = 0; w2 < WPB; ++w2) s += lds_red[w2];
        partial[blockIdx.x] = s;
    }
}

__global__ void scl_reduce_kernel(const float* __restrict__ partial,
                                  float* __restrict__ out) {
    const int t = threadIdx.x;
    float s = 0.f;
    for (int idx = t; idx < NBLOCKS; idx += 256) s += partial[idx];
    #pragma unroll
    for (int off = 32; off > 0; off >>= 1)
        s += __shfl_down(s, off, 64);
    __shared__ float red[4];
    if ((t & 63) == 0) red[t >> 6] = s;
    __syncthreads();
    if (t == 0) {
        float tot = (red[0] + red[1]) + (red[2] + red[3]);
        out[0] = tot * (1.0f / (8192.0f * 8192.0f));
    }
}

extern "C" void kernel_launch(void* const* d_in, const int* in_sizes, int n_in,
                              void* d_out, int out_size, void* d_ws, size_t ws_size,
                              hipStream_t stream) {
    const float* pred = (const float*)d_in[0];
    const float* spat = (const float*)d_in[1];
    float* out = (float*)d_out;

    float* sq      = (float*)d_ws;        // [0, NPTS)
    float* partial = sq + NPTS;           // [NPTS, NPTS + NBLOCKS)

    scl_sq_kernel<<<NPTS / 256, 256, 0, stream>>>(pred, sq);
    scl_main_kernel<<<NBLOCKS, 256, 0, stream>>>(pred, spat, sq, partial);
    scl_reduce_kernel<<<1, 256, 0, stream>>>(partial, out);
}

// Round 2
// 62.616 us; speedup vs baseline: 2.3674x; 2.3674x over previous
//
#include <hip/hip_runtime.h>
#include <hip/hip_bf16.h>

// SpatialCoherenceLoss on MI355X — R2: bf16 MFMA Gram matrix + fused epilogue.
// loss = mean_{i,j} exp(-100*||s_i-s_j||^2) * (sq_i + sq_j - 2*<p_i,p_j>)
// P is bf16-rounded once (prep); sq computed FROM the rounded values so
// pd == ||p~_i - p~_j||^2 exactly (consistent, unbiased ~0.1%/pair error).
// Dot products via mfma_f32_16x16x32_bf16; weights/epilogue in fp32 VALU.
// All data (1MB bf16 P + 128KB params) is L2-resident -> frags loaded
// directly from global, no LDS staging.

#define NPTS 8192
#define DIM  64
#define TILE 128
#define NT   (NPTS / TILE)   // 64 tiles per dim
#define NBLK (NT * NT)       // 4096 blocks

typedef __attribute__((ext_vector_type(8))) short bf16x8;  // MFMA A/B frag
typedef __attribute__((ext_vector_type(4))) float f32x4;   // MFMA C/D frag

__device__ __forceinline__ ushort f2bf(float x) {  // RNE fp32->bf16
    unsigned u = __builtin_bit_cast(unsigned, x);
    unsigned r = (u + 0x7fffu + ((u >> 16) & 1u)) >> 16;
    return (ushort)r;
}
__device__ __forceinline__ float bf2f(ushort b) {
    unsigned u = ((unsigned)b) << 16;
    return __builtin_bit_cast(float, u);
}

// One thread per point: round P row to bf16, sq from rounded values,
// pack {sq, sx, sy, 0} as float4.
__global__ void scl_prep_kernel(const float* __restrict__ pred,
                                const float* __restrict__ spat,
                                ushort* __restrict__ pbf,
                                float4* __restrict__ params) {
    int i = blockIdx.x * blockDim.x + threadIdx.x;
    const float4* pr = (const float4*)(pred + (size_t)i * DIM);
    ushort4* po = (ushort4*)(pbf + (size_t)i * DIM);
    float sq = 0.f;
    #pragma unroll
    for (int k = 0; k < DIM / 4; ++k) {
        float4 v = pr[k];
        ushort4 o;
        o.x = f2bf(v.x); o.y = f2bf(v.y); o.z = f2bf(v.z); o.w = f2bf(v.w);
        float a = bf2f(o.x), b = bf2f(o.y), c = bf2f(o.z), d = bf2f(o.w);
        sq += a * a + b * b + c * c + d * d;
        po[k] = o;
    }
    float4 pm;
    pm.x = sq; pm.y = spat[2 * i]; pm.z = spat[2 * i + 1]; pm.w = 0.f;
    params[i] = pm;
}

// Block = 4 waves = 128x128 tile. Wave w owns rows [wave*32, +32) x 128 cols:
// 2 rowblocks x 8 colblocks of 16x16 frags, K=64 = 2 mfma per frag.
// A/B frag layout (16x16x32): row(col)=lane&15, k=(lane>>4)*8 + elem.
// C/D layout (measured, m89): col=lane&15, row=(lane>>4)*4 + reg.
__launch_bounds__(256)
__global__ void scl_mfma_kernel(const ushort* __restrict__ pbf,
                                const float4* __restrict__ params,
                                float* __restrict__ partial) {
    const int lane = threadIdx.x & 63;
    const int wave = threadIdx.x >> 6;
    const int bi = blockIdx.x & (NT - 1);
    const int bj = blockIdx.x >> 6;
    const int ti = bi * TILE;
    const int tj = bj * TILE;
    const int fr = lane & 15;    // frag row (A) / col (B, C/D)
    const int h  = lane >> 4;    // k-group

    // A frags
    bf16x8 afrag[2][2];
    #pragma unroll
    for (int rb = 0; rb < 2; ++rb)
        #pragma unroll
        for (int ks = 0; ks < 2; ++ks) {
            int row = ti + wave * 32 + rb * 16 + fr;
            afrag[rb][ks] =
                *(const bf16x8*)(pbf + (size_t)row * DIM + ks * 32 + h * 8);
        }

    f32x4 acc[2][8];
    #pragma unroll
    for (int rb = 0; rb < 2; ++rb)
        #pragma unroll
        for (int cb = 0; cb < 8; ++cb)
            acc[rb][cb] = (f32x4){0.f, 0.f, 0.f, 0.f};

    #pragma unroll
    for (int cb = 0; cb < 8; ++cb) {
        int col = tj + cb * 16 + fr;
        bf16x8 b0 = *(const bf16x8*)(pbf + (size_t)col * DIM + 0 + h * 8);
        bf16x8 b1 = *(const bf16x8*)(pbf + (size_t)col * DIM + 32 + h * 8);
        #pragma unroll
        for (int rb = 0; rb < 2; ++rb) {
            acc[rb][cb] = __builtin_amdgcn_mfma_f32_16x16x32_bf16(
                afrag[rb][0], b0, acc[rb][cb], 0, 0, 0);
            acc[rb][cb] = __builtin_amdgcn_mfma_f32_16x16x32_bf16(
                afrag[rb][1], b1, acc[rb][cb], 0, 0, 0);
        }
    }

    // hoist row params (8 rows/lane)
    float rsq[2][4], rsx[2][4], rsy[2][4];
    #pragma unroll
    for (int rb = 0; rb < 2; ++rb)
        #pragma unroll
        for (int reg = 0; reg < 4; ++reg) {
            int i = ti + wave * 32 + rb * 16 + h * 4 + reg;
            float4 rp = params[i];
            rsq[rb][reg] = rp.x; rsx[rb][reg] = rp.y; rsy[rb][reg] = rp.z;
        }

    float loss = 0.f;
    #pragma unroll
    for (int cb = 0; cb < 8; ++cb) {
        float4 cp = params[tj + cb * 16 + fr];
        #pragma unroll
        for (int rb = 0; rb < 2; ++rb)
            #pragma unroll
            for (int reg = 0; reg < 4; ++reg) {
                float dot = acc[rb][cb][reg];
                float dx = rsx[rb][reg] - cp.y;
                float dy = rsy[rb][reg] - cp.z;
                float d2 = fmaf(dx, dx, dy * dy);
                // exp(-100*d2) = 2^(-100*log2(e)*d2)
                float w = __builtin_amdgcn_exp2f(d2 * -144.26950408889634f);
                float pd = fmaf(-2.f, dot, rsq[rb][reg] + cp.x);
                loss = fmaf(w, pd, loss);
            }
    }

    #pragma unroll
    for (int off = 32; off > 0; off >>= 1)
        loss += __shfl_down(loss, off, 64);
    __shared__ float red[4];
    if (lane == 0) red[wave] = loss;
    __syncthreads();
    if (threadIdx.x == 0)
        partial[blockIdx.x] = (red[0] + red[1]) + (red[2] + red[3]);
}

__global__ void scl_reduce_kernel(const float* __restrict__ partial,
                                  float* __restrict__ out) {
    const int t = threadIdx.x;
    float s = 0.f;
    for (int idx = t; idx < NBLK; idx += 256) s += partial[idx];
    #pragma unroll
    for (int off = 32; off > 0; off >>= 1)
        s += __shfl_down(s, off, 64);
    __shared__ float red[4];
    if ((t & 63) == 0) red[t >> 6] = s;
    __syncthreads();
    if (t == 0) {
        float tot = (red[0] + red[1]) + (red[2] + red[3]);
        out[0] = tot * (1.0f / (8192.0f * 8192.0f));
    }
}

extern "C" void kernel_launch(void* const* d_in, const int* in_sizes, int n_in,
                              void* d_out, int out_size, void* d_ws, size_t ws_size,
                              hipStream_t stream) {
    const float* pred = (const float*)d_in[0];
    const float* spat = (const float*)d_in[1];
    float* out = (float*)d_out;

    ushort* pbf    = (ushort*)d_ws;                                    // 1 MB
    float4* params = (float4*)((char*)d_ws + (size_t)NPTS * DIM * 2);  // 128 KB
    float* partial = (float*)((char*)params + NPTS * sizeof(float4));  // 16 KB

    scl_prep_kernel<<<NPTS / 256, 256, 0, stream>>>(pred, spat, pbf, params);
    scl_mfma_kernel<<<NBLK, 256, 0, stream>>>(pbf, params, partial);
    scl_reduce_kernel<<<1, 256, 0, stream>>>(partial, out);
}

// Round 3
// 55.181 us; speedup vs baseline: 2.6864x; 1.1347x over previous
//
#include <hip/hip_runtime.h>

// SpatialCoherenceLoss — R3: LDS-staged (global_load_lds + source-swizzle),
// triangular symmetry (bj>=bi, off-diag x2), last-block reduction.
// loss = mean_{i,j} exp(-100*||s_i-s_j||^2) * (sq_i + sq_j - 2<p_i,p_j>)
// P bf16-rounded once; sq from rounded values (pd == ||p~i - p~j||^2 exactly).

#define NPTS 8192
#define DIM  64
#define TILE 128
#define NT   (NPTS / TILE)            // 64
#define NBLK_TRI (NT * (NT + 1) / 2)  // 2080

typedef __attribute__((ext_vector_type(8))) short bf16x8;
typedef __attribute__((ext_vector_type(4))) float f32x4;

#define AS3(p) ((__attribute__((address_space(3))) void*)(p))
#define AS1(p) ((const __attribute__((address_space(1))) void*)(p))

__device__ __forceinline__ ushort f2bf(float x) {  // RNE fp32->bf16
    unsigned u = __builtin_bit_cast(unsigned, x);
    unsigned r = (u + 0x7fffu + ((u >> 16) & 1u)) >> 16;
    return (ushort)r;
}
__device__ __forceinline__ float bf2f(ushort b) {
    unsigned u = ((unsigned)b) << 16;
    return __builtin_bit_cast(float, u);
}

__global__ void scl_prep_kernel(const float* __restrict__ pred,
                                const float* __restrict__ spat,
                                ushort* __restrict__ pbf,
                                float4* __restrict__ params,
                                unsigned* __restrict__ ctr) {
    int i = blockIdx.x * blockDim.x + threadIdx.x;
    if (i == 0) ctr[0] = 0u;  // reset arrival counter every call
    const float4* pr = (const float4*)(pred + (size_t)i * DIM);
    ushort4* po = (ushort4*)(pbf + (size_t)i * DIM);
    float sq = 0.f;
    #pragma unroll
    for (int k = 0; k < DIM / 4; ++k) {
        float4 v = pr[k];
        ushort4 o;
        o.x = f2bf(v.x); o.y = f2bf(v.y); o.z = f2bf(v.z); o.w = f2bf(v.w);
        float a = bf2f(o.x), b = bf2f(o.y), c = bf2f(o.z), d = bf2f(o.w);
        sq += a * a + b * b + c * c + d * d;
        po[k] = o;
    }
    float4 pm;
    pm.x = sq; pm.y = spat[2 * i]; pm.z = spat[2 * i + 1]; pm.w = 0.f;
    params[i] = pm;
}

// Block = 4 waves = 128x128 tile (bi<=bj). smem: A[16KB] B[16KB] pA[2KB] pB[2KB].
// Swizzle: LDS linear dest; global source offset ^= ((row&7)<<4); ds_read
// applies the same XOR -> conflict-free b128 (uniform 8 lanes/bank-quad).
__launch_bounds__(256)
__global__ void scl_mfma_kernel(const ushort* __restrict__ pbf,
                                const float4* __restrict__ params,
                                float* __restrict__ partial,
                                unsigned* __restrict__ ctr,
                                float* __restrict__ out) {
    __shared__ __align__(16) char smem[36864];
    __shared__ float red[4];
    __shared__ int lastflag;

    const int lane = threadIdx.x & 63;
    const int wave = threadIdx.x >> 6;
    const int fr = lane & 15;
    const int h  = lane >> 4;

    // triangular decode (uniform scalar loop, <=64 iters)
    int t = blockIdx.x;
    int bi = 0, base = 0;
    while (base + (NT - bi) <= t) { base += NT - bi; ++bi; }
    const int bj = bi + (t - base);
    const int ti = bi * TILE, tj = bj * TILE;

    // ---- stage tiles + params into LDS ----
    {
        const char* gA = (const char*)(pbf + (size_t)ti * DIM);
        const char* gB = (const char*)(pbf + (size_t)tj * DIM);
        #pragma unroll
        for (int it = 0; it < 4; ++it) {
            unsigned L = (unsigned)threadIdx.x * 16u + (unsigned)it * 4096u;
            unsigned row = L >> 7;
            unsigned src = (L & ~127u) | ((L & 127u) ^ ((row & 7u) << 4));
            unsigned lbase = (unsigned)wave * 1024u + (unsigned)it * 4096u;
            __builtin_amdgcn_global_load_lds(AS1(gA + src), AS3(smem + lbase), 16, 0, 0);
            __builtin_amdgcn_global_load_lds(AS1(gB + src), AS3(smem + 16384 + lbase), 16, 0, 0);
        }
        // params: wave 0/1 -> A halves, wave 2/3 -> B halves
        const char* gp = (const char*)(params + (wave < 2 ? ti : tj));
        unsigned srcoff = (unsigned)(wave & 1) * 1024u + (unsigned)lane * 16u;
        __builtin_amdgcn_global_load_lds(AS1(gp + srcoff),
                                         AS3(smem + 32768 + (unsigned)wave * 1024u), 16, 0, 0);
        asm volatile("s_waitcnt vmcnt(0)" ::: "memory");
        __syncthreads();
    }

    // ---- A frags from LDS (swizzled read) ----
    bf16x8 afrag[2][2];
    #pragma unroll
    for (int rb = 0; rb < 2; ++rb)
        #pragma unroll
        for (int ks = 0; ks < 2; ++ks) {
            unsigned row = (unsigned)(wave * 32 + rb * 16 + fr);
            unsigned off = (unsigned)(ks * 64 + h * 16);
            afrag[rb][ks] = *(const bf16x8*)(smem + row * 128u + (off ^ ((row & 7u) << 4)));
        }

    f32x4 acc[2][8];
    #pragma unroll
    for (int rb = 0; rb < 2; ++rb)
        #pragma unroll
        for (int cb = 0; cb < 8; ++cb)
            acc[rb][cb] = (f32x4){0.f, 0.f, 0.f, 0.f};

    #pragma unroll
    for (int cb = 0; cb < 8; ++cb) {
        unsigned rowB = (unsigned)(cb * 16 + fr);
        unsigned sw = (rowB & 7u) << 4;
        const char* bb = smem + 16384 + rowB * 128u;
        bf16x8 b0 = *(const bf16x8*)(bb + (((unsigned)(h * 16)) ^ sw));
        bf16x8 b1 = *(const bf16x8*)(bb + (((unsigned)(64 + h * 16)) ^ sw));
        #pragma unroll
        for (int rb = 0; rb < 2; ++rb) {
            acc[rb][cb] = __builtin_amdgcn_mfma_f32_16x16x32_bf16(
                afrag[rb][0], b0, acc[rb][cb], 0, 0, 0);
            acc[rb][cb] = __builtin_amdgcn_mfma_f32_16x16x32_bf16(
                afrag[rb][1], b1, acc[rb][cb], 0, 0, 0);
        }
    }

    // ---- epilogue: params from LDS ----
    const float4* pAl = (const float4*)(smem + 32768);
    const float4* pBl = pAl + 128;

    float rsq[2][4], rsx[2][4], rsy[2][4];
    #pragma unroll
    for (int rb = 0; rb < 2; ++rb)
        #pragma unroll
        for (int reg = 0; reg < 4; ++reg) {
            float4 rp = pAl[wave * 32 + rb * 16 + h * 4 + reg];
            rsq[rb][reg] = rp.x; rsx[rb][reg] = rp.y; rsy[rb][reg] = rp.z;
        }

    float loss = 0.f;
    #pragma unroll
    for (int cb = 0; cb < 8; ++cb) {
        float4 cp = pBl[cb * 16 + fr];
        #pragma unroll
        for (int rb = 0; rb < 2; ++rb)
            #pragma unroll
            for (int reg = 0; reg < 4; ++reg) {
                float dot = acc[rb][cb][reg];
                float dx = rsx[rb][reg] - cp.y;
                float dy = rsy[rb][reg] - cp.z;
                float d2 = fmaf(dx, dx, dy * dy);
                float w = __builtin_amdgcn_exp2f(d2 * -144.26950408889634f);
                float pd = fmaf(-2.f, dot, rsq[rb][reg] + cp.x);
                loss = fmaf(w, pd, loss);
            }
    }

    #pragma unroll
    for (int off = 32; off > 0; off >>= 1)
        loss += __shfl_down(loss, off, 64);
    if (lane == 0) red[wave] = loss;
    __syncthreads();
    if (threadIdx.x == 0) {
        float s = (red[0] + red[1]) + (red[2] + red[3]);
        if (bi != bj) s *= 2.f;            // symmetry
        partial[blockIdx.x] = s;
        __threadfence();                   // release partial
        unsigned old = atomicAdd(ctr, 1u);
        lastflag = (old == (unsigned)(NBLK_TRI - 1)) ? 1 : 0;
        if (lastflag) __threadfence();     // acquire others' partials
    }
    __syncthreads();
    if (lastflag) {                        // block-uniform
        float s = 0.f;
        for (int idx = threadIdx.x; idx < NBLK_TRI; idx += 256)
            s += partial[idx];
        #pragma unroll
        for (int off = 32; off > 0; off >>= 1)
            s += __shfl_down(s, off, 64);
        if (lane == 0) red[wave] = s;
        __syncthreads();
        if (threadIdx.x == 0)
            out[0] = ((red[0] + red[1]) + (red[2] + red[3])) *
                     (1.0f / (8192.0f * 8192.0f));
    }
}

extern "C" void kernel_launch(void* const* d_in, const int* in_sizes, int n_in,
                              void* d_out, int out_size, void* d_ws, size_t ws_size,
                              hipStream_t stream) {
    const float* pred = (const float*)d_in[0];
    const float* spat = (const float*)d_in[1];
    float* out = (float*)d_out;

    ushort*   pbf     = (ushort*)d_ws;                                     // 1 MB
    float4*   params  = (float4*)((char*)d_ws + (size_t)NPTS * DIM * 2);   // 128 KB
    float*    partial = (float*)((char*)params + NPTS * sizeof(float4));   // 8.3 KB
    unsigned* ctr     = (unsigned*)(partial + ((NBLK_TRI + 3) & ~3));

    scl_prep_kernel<<<NPTS / 256, 256, 0, stream>>>(pred, spat, pbf, params, ctr);
    scl_mfma_kernel<<<NBLK_TRI, 256, 0, stream>>>(pbf, params, partial, ctr, out);
}

// Round 4
// 40.905 us; speedup vs baseline: 3.6240x; 1.3490x over previous
//
#include <hip/hip_runtime.h>

// SpatialCoherenceLoss — R4: persistent blocks (2 tiles each), double-buffered
// B staging (stage k+1 overlaps compute k), A-tile resident in regs across
// items sharing bi. Triangular symmetry, last-block reduction.
// loss = mean_{i,j} exp(-100*||s_i-s_j||^2) * (sq_i + sq_j - 2<p_i,p_j>)
// P bf16-rounded once; sq from rounded values. Coords pre-scaled by
// sqrt(100*log2(e)) so weight = exp2(-(dx^2+dy^2)) (neg via FMA modifiers).

#define NPTS 8192
#define DIM  64
#define TILE 128
#define NT   (NPTS / TILE)             // 64
#define NITEMS (NT * (NT + 1) / 2)     // 2080
#define IPB  2
#define NBLK (NITEMS / IPB)            // 1040

typedef __attribute__((ext_vector_type(8))) short bf16x8;
typedef __attribute__((ext_vector_type(4))) float f32x4;

#define AS3(p) ((__attribute__((address_space(3))) void*)(p))
#define AS1(p) ((const __attribute__((address_space(1))) void*)(p))

__device__ __forceinline__ ushort f2bf(float x) {
    unsigned u = __builtin_bit_cast(unsigned, x);
    unsigned r = (u + 0x7fffu + ((u >> 16) & 1u)) >> 16;
    return (ushort)r;
}
__device__ __forceinline__ float bf2f(ushort b) {
    unsigned u = ((unsigned)b) << 16;
    return __builtin_bit_cast(float, u);
}

constexpr float kCoordScale = 12.0112244f;  // sqrt(100*log2(e))

__global__ void scl_prep_kernel(const float* __restrict__ pred,
                                const float* __restrict__ spat,
                                ushort* __restrict__ pbf,
                                float4* __restrict__ params,
                                unsigned* __restrict__ ctr) {
    int i = blockIdx.x * blockDim.x + threadIdx.x;
    if (i == 0) ctr[0] = 0u;
    const float4* pr = (const float4*)(pred + (size_t)i * DIM);
    ushort4* po = (ushort4*)(pbf + (size_t)i * DIM);
    float sq = 0.f;
    #pragma unroll
    for (int k = 0; k < DIM / 4; ++k) {
        float4 v = pr[k];
        ushort4 o;
        o.x = f2bf(v.x); o.y = f2bf(v.y); o.z = f2bf(v.z); o.w = f2bf(v.w);
        float a = bf2f(o.x), b = bf2f(o.y), c = bf2f(o.z), d = bf2f(o.w);
        sq += a * a + b * b + c * c + d * d;
        po[k] = o;
    }
    float4 pm;
    pm.x = sq;
    pm.y = spat[2 * i] * kCoordScale;
    pm.z = spat[2 * i + 1] * kCoordScale;
    pm.w = 0.f;
    params[i] = pm;
}

// LDS: B0[16K) B1[16K) P0[2K) P1[2K)  = 36 KB (+red) -> 4 blocks/CU.
__launch_bounds__(256)
__global__ void scl_mfma_kernel(const ushort* __restrict__ pbf,
                                const float4* __restrict__ params,
                                float* __restrict__ partial,
                                unsigned* __restrict__ ctr,
                                float* __restrict__ out) {
    __shared__ __align__(16) char smem[36864];
    __shared__ float red[4];
    __shared__ int lastflag;

    const int tid  = threadIdx.x;
    const int lane = tid & 63;
    const int wave = tid >> 6;
    const int fr = lane & 15;
    const int h  = lane >> 4;

    // decode first item (scalar, <=64 iters)
    int t = blockIdx.x * IPB;
    int bi = 0, base = 0;
    while (base + (NT - bi) <= t) { base += NT - bi; ++bi; }
    int bj = bi + (t - base);

    // ---- A tile (frags + row params) for current bi ----
    bf16x8 afrag[2][2];
    float rsq[2][4], rsx[2][4], rsy[2][4];
    auto loadA = [&](int bi_) {
        int ti = bi_ * TILE;
        #pragma unroll
        for (int rb = 0; rb < 2; ++rb) {
            int row = ti + wave * 32 + rb * 16 + fr;
            #pragma unroll
            for (int ks = 0; ks < 2; ++ks)
                afrag[rb][ks] =
                    *(const bf16x8*)(pbf + (size_t)row * DIM + ks * 32 + h * 8);
            #pragma unroll
            for (int reg = 0; reg < 4; ++reg) {
                float4 rp = params[ti + wave * 32 + rb * 16 + h * 4 + reg];
                rsq[rb][reg] = rp.x; rsx[rb][reg] = rp.y; rsy[rb][reg] = rp.z;
            }
        }
    };

    auto stageB = [&](int bj_, int buf) {
        const char* gB = (const char*)(pbf + (size_t)bj_ * TILE * DIM);
        #pragma unroll
        for (int it = 0; it < 4; ++it) {
            unsigned L = (unsigned)tid * 16u + (unsigned)it * 4096u;
            unsigned row = L >> 7;
            unsigned src = (L & ~127u) | ((L & 127u) ^ ((row & 7u) << 4));
            unsigned dst = (unsigned)buf * 16384u + (unsigned)wave * 1024u +
                           (unsigned)it * 4096u;
            __builtin_amdgcn_global_load_lds(AS1(gB + src), AS3(smem + dst), 16, 0, 0);
        }
        if (wave < 2) {
            const char* gp = (const char*)(params + bj_ * TILE);
            unsigned so = (unsigned)wave * 1024u + (unsigned)lane * 16u;
            __builtin_amdgcn_global_load_lds(
                AS1(gp + so),
                AS3(smem + 32768u + (unsigned)buf * 2048u + (unsigned)wave * 1024u),
                16, 0, 0);
        }
    };

    loadA(bi);          // older than stage DMAs -> waits won't drain prefetch
    int abi = bi;
    stageB(bj, 0);

    float loss = 0.f;
    int cur = 0, cbi = bi, cbj = bj;
    #pragma unroll 1
    for (int k = 0; k < IPB; ++k) {
        int nbi = cbi, nbj = cbj + 1;
        if (nbj == NT) { nbi = cbi + 1; nbj = nbi; }

        asm volatile("s_waitcnt vmcnt(0)" ::: "memory");
        __syncthreads();                       // buf[cur] ready

        if (cbi != abi) { loadA(cbi); abi = cbi; }
        if (k + 1 < IPB) stageB(nbj, cur ^ 1); // prefetch under compute

        const char* bB = smem + (unsigned)cur * 16384u;
        const float4* pBl = (const float4*)(smem + 32768u + (unsigned)cur * 2048u);

        float tl = 0.f;
        #pragma unroll
        for (int half = 0; half < 2; ++half) {
            f32x4 acc[2][4];
            #pragma unroll
            for (int rb = 0; rb < 2; ++rb)
                #pragma unroll
                for (int c4 = 0; c4 < 4; ++c4)
                    acc[rb][c4] = (f32x4){0.f, 0.f, 0.f, 0.f};

            #pragma unroll
            for (int c4 = 0; c4 < 4; ++c4) {
                unsigned rowB = (unsigned)((half * 4 + c4) * 16 + fr);
                unsigned sw = (rowB & 7u) << 4;
                const char* bb = bB + rowB * 128u;
                bf16x8 b0 = *(const bf16x8*)(bb + (((unsigned)(h * 16)) ^ sw));
                bf16x8 b1 = *(const bf16x8*)(bb + (((unsigned)(64 + h * 16)) ^ sw));
                #pragma unroll
                for (int rb = 0; rb < 2; ++rb) {
                    acc[rb][c4] = __builtin_amdgcn_mfma_f32_16x16x32_bf16(
                        afrag[rb][0], b0, acc[rb][c4], 0, 0, 0);
                    acc[rb][c4] = __builtin_amdgcn_mfma_f32_16x16x32_bf16(
                        afrag[rb][1], b1, acc[rb][c4], 0, 0, 0);
                }
            }

            #pragma unroll
            for (int c4 = 0; c4 < 4; ++c4) {
                float4 cp = pBl[(half * 4 + c4) * 16 + fr];
                #pragma unroll
                for (int rb = 0; rb < 2; ++rb)
                    #pragma unroll
                    for (int reg = 0; reg < 4; ++reg) {
                        float dot = acc[rb][c4][reg];
                        float dx = rsx[rb][reg] - cp.y;
                        float dy = rsy[rb][reg] - cp.z;
                        float nd2 = fmaf(-dx, dx, (-dy) * dy);  // -(dx^2+dy^2)
                        float w = __builtin_amdgcn_exp2f(nd2);
                        float pd = fmaf(-2.f, dot, rsq[rb][reg] + cp.x);
                        tl = fmaf(w, pd, tl);
                    }
            }
        }
        loss += (cbi != cbj) ? 2.f * tl : tl;
        cur ^= 1; cbi = nbi; cbj = nbj;
    }

    #pragma unroll
    for (int off = 32; off > 0; off >>= 1)
        loss += __shfl_down(loss, off, 64);
    if (lane == 0) red[wave] = loss;
    __syncthreads();
    if (tid == 0) {
        partial[blockIdx.x] = (red[0] + red[1]) + (red[2] + red[3]);
        __threadfence();
        unsigned old = atomicAdd(ctr, 1u);
        lastflag = (old == (unsigned)(NBLK - 1)) ? 1 : 0;
        if (lastflag) __threadfence();
    }
    __syncthreads();
    if (lastflag) {
        float s = 0.f;
        for (int idx = tid; idx < NBLK; idx += 256) s += partial[idx];
        #pragma unroll
        for (int off = 32; off > 0; off >>= 1)
            s += __shfl_down(s, off, 64);
        if (lane == 0) red[wave] = s;
        __syncthreads();
        if (tid == 0)
            out[0] = ((red[0] + red[1]) + (red[2] + red[3])) *
                     (1.0f / (8192.0f * 8192.0f));
    }
}

extern "C" void kernel_launch(void* const* d_in, const int* in_sizes, int n_in,
                              void* d_out, int out_size, void* d_ws, size_t ws_size,
                              hipStream_t stream) {
    const float* pred = (const float*)d_in[0];
    const float* spat = (const float*)d_in[1];
    float* out = (float*)d_out;

    ushort*   pbf     = (ushort*)d_ws;                                    // 1 MB
    float4*   params  = (float4*)((char*)d_ws + (size_t)NPTS * DIM * 2);  // 128 KB
    float*    partial = (float*)((char*)params + NPTS * sizeof(float4));  // 4.2 KB
    unsigned* ctr     = (unsigned*)(partial + ((NBLK + 3) & ~3));

    scl_prep_kernel<<<NPTS / 256, 256, 0, stream>>>(pred, spat, pbf, params, ctr);
    scl_mfma_kernel<<<NBLK, 256, 0, stream>>>(pbf, params, partial, ctr, out);
}